// Round 3
// baseline (455.556 us; speedup 1.0000x reference)
//
#include <hip/hip_runtime.h>
#include <hip/hip_bf16.h>
#include <math.h>

typedef unsigned short u16;
typedef unsigned int u32;

#define Bz 2
#define Sz 2048
#define Dz 2048
#define Hz 16
#define HDz 128
#define Mz 4096

typedef __bf16 bf16x8 __attribute__((ext_vector_type(8)));
typedef float f32x4 __attribute__((ext_vector_type(4)));

__device__ __forceinline__ float bf2f(u16 h) {
    union { u32 u; float f; } x; x.u = ((u32)h) << 16; return x.f;
}
__device__ __forceinline__ u16 f2bf(float f) {
    union { float f; u32 u; } x; x.f = f;
    u32 u = x.u;
    return (u16)((u + 0x7FFFu + ((u >> 16) & 1u)) >> 16);
}
// truncating pack (hot path; P in [0,1], bias cancels via consistent l)
__device__ __forceinline__ u32 pack_bf16_trunc(float lo, float hi) {
    union { float f; u32 u; } a, b; a.f = lo; b.f = hi;
    return (a.u >> 16) | (b.u & 0xFFFF0000u);
}
__device__ __forceinline__ u32 pack_bf16_rn(float lo, float hi) {
    return (u32)f2bf(lo) | ((u32)f2bf(hi) << 16);
}
__device__ __forceinline__ float fexp2(float x) {
#if __has_builtin(__builtin_amdgcn_exp2f)
    return __builtin_amdgcn_exp2f(x);
#else
    return exp2f(x);
#endif
}
// async global->LDS, 16B per lane; lds dest = uniform base + lane*16
__device__ __forceinline__ void gl_lds16(const void* g, void* l) {
    __builtin_amdgcn_global_load_lds(
        (const __attribute__((address_space(1))) void*)g,
        (__attribute__((address_space(3))) void*)l, 16, 0, 0);
}

// ---------------- fp32 -> bf16 convert (x) ---------------------------------
__global__ void cvt_f32_bf16(const float* __restrict__ src, u16* __restrict__ dst) {
    size_t i = (size_t)blockIdx.x * blockDim.x + threadIdx.x;  // one per 8 elems
    float4 a = ((const float4*)src)[2 * i];
    float4 b = ((const float4*)src)[2 * i + 1];
    u16 r[8] = {f2bf(a.x), f2bf(a.y), f2bf(a.z), f2bf(a.w),
                f2bf(b.x), f2bf(b.y), f2bf(b.z), f2bf(b.w)};
    *(uint4*)(dst + 8 * i) = *(const uint4*)r;
}

// ---------------- weight transpose+convert: Wt[n][k] = bf16(W[k][n]) -------
__global__ void transpose_w(const float* __restrict__ W0, const float* __restrict__ W1,
                            const float* __restrict__ W2, const float* __restrict__ W3,
                            u16* __restrict__ Wt) {
    __shared__ u16 t[64][65];
    const float* src = (blockIdx.z == 0) ? W0 : (blockIdx.z == 1) ? W1
                     : (blockIdx.z == 2) ? W2 : W3;
    u16* dst = Wt + (size_t)blockIdx.z * (Dz * Dz);
    int x = blockIdx.x * 64, y = blockIdx.y * 64;
    int c = threadIdx.x & 63, rb = (threadIdx.x >> 6) * 16;
#pragma unroll
    for (int i = 0; i < 16; i++) {
        int r = rb + i;
        t[r][c] = f2bf(src[(size_t)(y + r) * Dz + x + c]);
    }
    __syncthreads();
#pragma unroll
    for (int i = 0; i < 16; i++) {
        int r = rb + i;
        dst[(size_t)(x + r) * Dz + y + c] = t[c][r];
    }
}

// ---------------- GEMM: C = A[M,K](bf16) * Wt[N,K]^T(bf16), 128x128 tile ----
// (m97-structure; kept for the output projection where only 128 256^2-tiles
// exist and the big kernel would idle half the CUs)
template <int MODE>
__global__ void gemm_bt(const u16* __restrict__ A, const u16* __restrict__ BtBase,
                        void* __restrict__ CBase) {
    const int z = blockIdx.z;
    const u16* Bt = BtBase + (size_t)z * (Dz * Dz);
    const int tid = threadIdx.x, lane = tid & 63, wave = tid >> 6;
    const int ln = lane & 15, qd = lane >> 4;
    const int m0 = blockIdx.y * 128, n0 = blockIdx.x * 128;

    __shared__ __align__(16) u16 As[128][64];
    __shared__ __align__(16) u16 Bs[128][64];

    f32x4 acc[4][4];
#pragma unroll
    for (int i = 0; i < 4; i++)
#pragma unroll
        for (int j = 0; j < 4; j++) acc[i][j] = (f32x4){0.f, 0.f, 0.f, 0.f};

    const int wm = (wave >> 1) * 64, wn = (wave & 1) * 64;
    const int lr8 = lane >> 3;                         // row-within-8 (= row&7)
    const int bgo = (((lane & 7) ^ lr8) * 8);          // swizzled u16 col offset
    const int x7 = ln & 7;

    for (int k0 = 0; k0 < Dz; k0 += 64) {
        const u16* ga = A  + (size_t)(m0 + wave * 32 + lr8) * Dz + k0 + bgo;
        const u16* gb = Bt + (size_t)(n0 + wave * 32 + lr8) * Dz + k0 + bgo;
#pragma unroll
        for (int i = 0; i < 4; i++) {
            gl_lds16(ga + (size_t)(8 * i) * Dz, &As[wave * 32 + 8 * i][0]);
            gl_lds16(gb + (size_t)(8 * i) * Dz, &Bs[wave * 32 + 8 * i][0]);
        }
        __syncthreads();
#pragma unroll
        for (int kc = 0; kc < 2; kc++) {
            bf16x8 af[4], bff[4];
            const int cs = ((4 * kc + qd) ^ x7) * 8;   // swizzled fragment col
#pragma unroll
            for (int i = 0; i < 4; i++) {
                af[i]  = *(const bf16x8*)&As[wm + i * 16 + ln][cs];
                bff[i] = *(const bf16x8*)&Bs[wn + i * 16 + ln][cs];
            }
#pragma unroll
            for (int i = 0; i < 4; i++)
#pragma unroll
                for (int j = 0; j < 4; j++)
                    acc[i][j] = __builtin_amdgcn_mfma_f32_16x16x32_bf16(
                        af[i], bff[j], acc[i][j], 0, 0, 0);
        }
        __syncthreads();
    }

#pragma unroll
    for (int i = 0; i < 4; i++) {
#pragma unroll
        for (int j = 0; j < 4; j++) {
#pragma unroll
            for (int r = 0; r < 4; r++) {
                int row = m0 + wm + i * 16 + qd * 4 + r;
                int col = n0 + wn + j * 16 + ln;
                if (MODE == 0) {
                    ((float*)CBase)[(size_t)row * Dz + col] = acc[i][j][r];
                } else {
                    u16* C = (u16*)CBase + (size_t)z * ((size_t)Mz * Dz);
                    u16 hv = f2bf(acc[i][j][r]);
                    int bb = row >> 11, ss = row & 2047;
                    int hh = col >> 7, hd = col & 127;
                    if (z == 2)
                        C[((size_t)(bb * Hz + hh) * HDz + hd) * Sz + ss] = hv;
                    else
                        C[((size_t)(bb * Hz + hh) * Sz + ss) * HDz + hd] = hv;
                }
            }
        }
    }
}

// ---------------- 256x256 8-phase GEMM (QKV projection) ---------------------
// BM=BN=256, BK=64, 8 waves (2M x 4N), per-wave output 128x64.
// LDS 128 KiB: As/Bs [2 buf][256][64], 8-way XOR block-swizzle; staged via
// global_load_lds with inverse-swizzled global source (linear LDS dest).
// REGISTER-REUSE phase schedule (m201-style, 28 ds_read_b128 per K-tile/wave):
//   quadrants (0,0)->(0,1)->(1,1)->(1,0); reads per phase {12,4,8,4}:
//   P-A: af<-A0, bf0<-B0; P-B: bf1<-B1 (af reused); P-C: af<-A1 (bf1 reused);
//   P-D: bf0<-B0 re-read (af reused).
// Staging rotation (one 2-issue STAGE per phase; no slot staged in a phase
// that reads it; every slot staged >=1 barrier after its last reader):
//   P1: b1.B0<-k1  P2: b1.A1<-k1  P3: b0.B1<-k2  P4: b0.A0<-k2 +vm4
//   P5: b0.B0<-k2  P6: b0.A1<-k2  P7: b1.B1<-k3  P8: b1.A0<-k3 +vm4
// vm4@P4 completes {prevP7,prevP8,P1,P2} -> b1.{B1,A0,B0,A1} land before
// P5..P7 read them; vm4@P8 completes {P3..P6} -> b0 fully landed before next
// iteration's P1. Counted vmcnt never drains to 0 in the loop.
#define G256_STAGE_A(BUF, MH, KOFS) do {                                        \
    gl_lds16(gA0 + (size_t)(MH) * 64 * Dz + (KOFS), &As[BUF][sa0 + (MH) * 64][0]); \
    gl_lds16(gA1 + (size_t)(MH) * 64 * Dz + (KOFS), &As[BUF][sa1 + (MH) * 64][0]); \
} while (0)
#define G256_STAGE_B(BUF, NH, KOFS) do {                                        \
    gl_lds16(gB0 + (size_t)(NH) * 32 * Dz + (KOFS), &Bs[BUF][sb0 + (NH) * 32][0]); \
    gl_lds16(gB1 + (size_t)(NH) * 32 * Dz + (KOFS), &Bs[BUF][sb1 + (NH) * 32][0]); \
} while (0)

#define G256_RD_A(BUF, MH) do {                                                 \
    _Pragma("unroll")                                                           \
    for (int kc = 0; kc < 2; ++kc) {                                            \
        const int cs = ((4 * kc + qd) ^ x7) * 8;                                \
        _Pragma("unroll")                                                       \
        for (int m = 0; m < 4; ++m)                                             \
            af[m][kc] = *(const bf16x8*)&As[BUF][wr * 128 + (MH) * 64 + m * 16 + ln][cs]; \
    }                                                                           \
} while (0)
#define G256_RD_B(BUF, NH, ARR) do {                                            \
    _Pragma("unroll")                                                           \
    for (int kc = 0; kc < 2; ++kc) {                                            \
        const int cs = ((4 * kc + qd) ^ x7) * 8;                                \
        _Pragma("unroll")                                                       \
        for (int n = 0; n < 2; ++n)                                             \
            ARR[n][kc] = *(const bf16x8*)&Bs[BUF][wc * 64 + (NH) * 32 + n * 16 + ln][cs]; \
    }                                                                           \
} while (0)
#define G256_MM(MH, NH, ARR) do {                                               \
    __builtin_amdgcn_s_setprio(1);                                              \
    _Pragma("unroll")                                                           \
    for (int kc = 0; kc < 2; ++kc)                                              \
        _Pragma("unroll")                                                       \
        for (int m = 0; m < 4; ++m)                                             \
            _Pragma("unroll")                                                   \
            for (int n = 0; n < 2; ++n)                                         \
                acc[(MH) * 4 + m][(NH) * 2 + n] =                               \
                    __builtin_amdgcn_mfma_f32_16x16x32_bf16(                    \
                        af[m][kc], ARR[n][kc],                                  \
                        acc[(MH) * 4 + m][(NH) * 2 + n], 0, 0, 0);              \
    __builtin_amdgcn_s_setprio(0);                                              \
} while (0)
#define G256_BAR do {                                                           \
    asm volatile("s_barrier" ::: "memory");                                     \
    __builtin_amdgcn_sched_barrier(0);                                          \
} while (0)
#define G256_LG8 asm volatile("s_waitcnt lgkmcnt(8)" ::: "memory")
#define G256_VM4 asm volatile("s_waitcnt vmcnt(4)" ::: "memory")

__global__ __launch_bounds__(512, 2)
void gemm256_qkv(const u16* __restrict__ A, const u16* __restrict__ BtBase,
                 u16* __restrict__ CBase) {
    const int z = blockIdx.z;
    const u16* Bt = BtBase + (size_t)z * (Dz * Dz);
    const int tid = threadIdx.x, lane = tid & 63, w = tid >> 6;
    const int ln = lane & 15, qd = lane >> 4;
    const int x7 = ln & 7;
    const int wr = w >> 2, wc = w & 3;                 // 2M x 4N wave grid
    const int m0 = blockIdx.y * 256, n0 = blockIdx.x * 256;

    __shared__ __align__(16) u16 As[2][256][64];       // 64 KiB
    __shared__ __align__(16) u16 Bs[2][256][64];       // 64 KiB

    f32x4 acc[8][4];
#pragma unroll
    for (int i = 0; i < 8; ++i)
#pragma unroll
        for (int j = 0; j < 4; ++j) acc[i][j] = (f32x4){0.f, 0.f, 0.f, 0.f};

    // staging maps: wave w stages segments {2w, 2w+1} (8 rows each) of a
    // 128-row half-tile; lane l covers row seg+(l>>3), 16B-block l&7, whose
    // data comes from global block (l&7)^(l>>3) (inverse swizzle).
    const int l8 = lane >> 3;
    const int cblk = ((lane & 7) ^ l8) * 8;            // u16 col offset in K
    const int sa0 = ((w >= 4) ? 128 : 0) + (((2 * w) & 7) * 8);
    const int sa1 = ((w >= 4) ? 128 : 0) + (((2 * w + 1) & 7) * 8);
    const int sb0 = (w >> 1) * 64 + (((2 * w) & 3) * 8);
    const int sb1 = (w >> 1) * 64 + (((2 * w + 1) & 3) * 8);
    const u16* gA0 = A + (size_t)(m0 + sa0 + l8) * Dz + cblk;
    const u16* gA1 = A + (size_t)(m0 + sa1 + l8) * Dz + cblk;
    const u16* gB0 = Bt + (size_t)(n0 + sb0 + l8) * Dz + cblk;
    const u16* gB1 = Bt + (size_t)(n0 + sb1 + l8) * Dz + cblk;

    bf16x8 af[4][2], bf0[2][2], bf1[2][2];

    // prologue: buf0 complete (8 issues) + b1.B1,b1.A0 @k=64 ("prev P7/P8",
    // 4 issues); vmcnt(4) -> all 8 buf0 issues landed. Loop invariant entering
    // P1: outstanding = {b1.B1, b1.A0}.
    G256_STAGE_A(0, 0, 0); G256_STAGE_B(0, 0, 0);
    G256_STAGE_B(0, 1, 0); G256_STAGE_A(0, 1, 0);
    G256_STAGE_B(1, 1, 64); G256_STAGE_A(1, 0, 64);
    G256_VM4;
    asm volatile("s_barrier" ::: "memory");

#pragma unroll 1
    for (int it = 0; it < Dz / 128; ++it) {
        const int kb = it * 128;
        const int k1 = kb + 64;
        // last iteration: restage valid-but-dead addresses to keep the
        // per-phase vmcnt counts uniform (data never read)
        const int k2 = (kb + 128 < Dz) ? (kb + 128) : (Dz - 128);
        const int k3 = (kb + 192 < Dz) ? (kb + 192) : (Dz - 64);

        // ---- buf0, tile 2*it ----
        // P1 (0,0): read af<-A0, bf0<-B0 (12 reads)
        G256_RD_A(0, 0); G256_RD_B(0, 0, bf0);
        G256_STAGE_B(1, 0, k1);
        G256_LG8;
        G256_BAR;
        G256_MM(0, 0, bf0);
        G256_BAR;
        // P2 (0,1): read bf1<-B1 (4 reads), af reused
        G256_RD_B(0, 1, bf1);
        G256_STAGE_A(1, 1, k1);
        G256_BAR;
        G256_MM(0, 1, bf1);
        G256_BAR;
        // P3 (1,1): read af<-A1 (8 reads), bf1 reused
        G256_RD_A(0, 1);
        G256_STAGE_B(0, 1, k2);
        G256_BAR;
        G256_MM(1, 1, bf1);
        G256_BAR;
        // P4 (1,0): read bf0<-B0 (4 reads), af reused
        G256_RD_B(0, 0, bf0);
        G256_STAGE_A(0, 0, k2);
        G256_BAR;
        G256_MM(1, 0, bf0);
        G256_VM4;
        G256_BAR;

        // ---- buf1, tile 2*it+1 ----
        // P5 (0,0)
        G256_RD_A(1, 0); G256_RD_B(1, 0, bf0);
        G256_STAGE_B(0, 0, k2);
        G256_LG8;
        G256_BAR;
        G256_MM(0, 0, bf0);
        G256_BAR;
        // P6 (0,1)
        G256_RD_B(1, 1, bf1);
        G256_STAGE_A(0, 1, k2);
        G256_BAR;
        G256_MM(0, 1, bf1);
        G256_BAR;
        // P7 (1,1)
        G256_RD_A(1, 1);
        G256_STAGE_B(1, 1, k3);
        G256_BAR;
        G256_MM(1, 1, bf1);
        G256_BAR;
        // P8 (1,0)
        G256_RD_B(1, 0, bf0);
        G256_STAGE_A(1, 0, k3);
        G256_BAR;
        G256_MM(1, 0, bf0);
        G256_VM4;
        G256_BAR;
    }

    // drain remaining staging loads before LDS goes out of scope
    asm volatile("s_waitcnt vmcnt(0)" ::: "memory");

    // epilogue: bf16 scatter, same layout as gemm_bt<1>
    u16* C = CBase + (size_t)z * ((size_t)Mz * Dz);
#pragma unroll
    for (int i = 0; i < 8; ++i) {
#pragma unroll
        for (int j = 0; j < 4; ++j) {
#pragma unroll
            for (int r = 0; r < 4; ++r) {
                int row = m0 + wr * 128 + i * 16 + qd * 4 + r;
                int col = n0 + wc * 64 + j * 16 + ln;
                u16 hv = f2bf(acc[i][j][r]);
                int bb = row >> 11, ss = row & 2047;
                int hh = col >> 7, hd = col & 127;
                if (z == 2)
                    C[((size_t)(bb * Hz + hh) * HDz + hd) * Sz + ss] = hv;
                else
                    C[((size_t)(bb * Hz + hh) * Sz + ss) * HDz + hd] = hv;
            }
        }
    }
}

// ---------------- RoPE in place; Q additionally scaled by SCALE*log2e ------
__global__ void rope_kernel(u16* __restrict__ Q, u16* __restrict__ Kk) {
    u32 idx = blockIdx.x * blockDim.x + threadIdx.x;   // 2^23 threads
    int isK = (idx >> 22) & 1;
    u16* T = isK ? Kk : Q;
    u32 p = idx & 0x3FFFFFu;                           // pair index within tensor
    int j = p & 63;
    int s = (p >> 6) & 2047;
    size_t base = (size_t)(p >> 6) * HDz + 2 * j;
    u32 u = *(u32*)(T + base);
    float x0 = bf2f((u16)(u & 0xFFFFu));
    float x1 = bf2f((u16)(u >> 16));
    int i0 = (2 * j) & 63;
    const float LG = 0.20762050593046017f;             // log2(10000)/64
    float f0 = exp2f(-LG * (float)i0);
    float f1 = exp2f(-LG * (float)(i0 + 1));
    float th0 = (float)s * f0, th1 = (float)s * f1;
    float s0, c0, s1, c1;
    sincosf(th0, &s0, &c0);
    sincosf(th1, &s1, &c1);
    // 1/sqrt(HD) * log2(e), folded into Q so flash works in exp2 domain
    float scl = isK ? 1.0f : 0.12751771218027603f;
    float y0 = (x0 * c0 - x1 * s0) * scl;
    float y1 = (x1 * c1 + x0 * s1) * scl;
    u32 outw = (u32)f2bf(y0) | ((u32)f2bf(y1) << 16);
    *(u32*)(T + base) = outw;
}

// ---------------- causal flash attention, S^T formulation ------------------
// Q,K: [B,H,S,HD] (Q pre-scaled); Vt: [B,H,HD,S]; O: [B,S,H*HD].
// Block: 4 waves x 16 q-cols = 64 q; k-tiles of 64 keys.
// S^T = K*Q^T; O^T = V^T*P^T; l via ones-row of V. XOR-swizzled Ks/Vs.
__global__ __launch_bounds__(256, 4)
void flash_attn(const u16* __restrict__ Q, const u16* __restrict__ Kk,
                const u16* __restrict__ Vt, u16* __restrict__ O) {
    const int tid = threadIdx.x, lane = tid & 63, wave = tid >> 6;
    const int ln = lane & 15, qd = lane >> 4;
    const int bh = blockIdx.x & 31;
    const int qt = 31 - (blockIdx.x >> 5);             // heavy q-tiles first
    const int b = bh >> 4, h = bh & 15;
    const int q0 = qt * 64;
    const u16* Qh = Q  + (size_t)bh * Sz * HDz;
    const u16* Kh = Kk + (size_t)bh * Sz * HDz;
    const u16* Vh = Vt + (size_t)bh * HDz * Sz;

    __shared__ __align__(16) u16 Ks[64][128];          // [key][d], swizzled blocks
    __shared__ __align__(16) u16 Vs[144][64];          // [d][key], swizzled; rows 128..143 ones-block

    // init ones-row block of Vs (row-uniform -> swizzle-invariant)
    for (int idx = tid; idx < 16 * 64; idx += 256) {
        int rr = idx >> 6, cc = idx & 63;
        Vs[128 + rr][cc] = (rr == 0) ? (u16)0x3F80 : (u16)0;
    }

    // Q B-fragments, direct from global (q = ln column, k = qd*8 + j)
    const int qabs = q0 + wave * 16 + ln;
    bf16x8 qf[4];
#pragma unroll
    for (int kc = 0; kc < 4; kc++) {
        uint4 t = *(const uint4*)(Qh + (size_t)qabs * HDz + kc * 32 + qd * 8);
        qf[kc] = *(const bf16x8*)&t;
    }

    float m_run = -INFINITY;
    f32x4 oa[9];                                       // O^T[d][q=ln]; oa[8] = l row
#pragma unroll
    for (int n = 0; n < 9; n++) oa[n] = (f32x4){0.f, 0.f, 0.f, 0.f};

    const int x7 = ln & 7;
    const int l4 = lane >> 4, c16 = lane & 15;         // K staging map
    const int lr8 = lane >> 3;                         // V staging map
    const int bgv = ((lane & 7) ^ lr8) * 8;

    for (int k0 = 0; k0 <= q0; k0 += 64) {
        // async stage K (64x128) and V (128x64), swizzled
        {
#pragma unroll
            for (int i = 0; i < 4; i++) {
                int rw = 4 * (i & 1) + l4;             // (row & 7)
                const u16* gk = Kh + (size_t)(k0 + 16 * wave + 4 * i + l4) * HDz
                                   + ((c16 ^ rw) * 8);
                gl_lds16(gk, &Ks[16 * wave + 4 * i][0]);
            }
            const u16* gv = Vh + (size_t)(32 * wave + lr8) * Sz + k0 + bgv;
#pragma unroll
            for (int i = 0; i < 4; i++)
                gl_lds16(gv + (size_t)(8 * i) * Sz, &Vs[32 * wave + 8 * i][0]);
        }
        __syncthreads();

        // S^T tile: C[key=mt*16+qd*4+r][q=ln]
        f32x4 sc4[4];
#pragma unroll
        for (int mt = 0; mt < 4; mt++) sc4[mt] = (f32x4){0.f, 0.f, 0.f, 0.f};
#pragma unroll
        for (int kc = 0; kc < 4; kc++) {
            const int cs = ((4 * kc + qd) ^ x7) * 8;
#pragma unroll
            for (int mt = 0; mt < 4; mt++) {
                bf16x8 kf = *(const bf16x8*)&Ks[mt * 16 + ln][cs];
                sc4[mt] = __builtin_amdgcn_mfma_f32_16x16x32_bf16(kf, qf[kc], sc4[mt], 0, 0, 0);
            }
        }
        if (k0 == q0) {                                // causal mask, diagonal tile only
#pragma unroll
            for (int mt = 0; mt < 4; mt++)
#pragma unroll
                for (int r = 0; r < 4; r++)
                    if (mt * 16 + qd * 4 + r > 16 * wave + ln) sc4[mt][r] = -3e38f;
        }

        // row max: in-register + cross-quad
        float rm = -3e38f;
#pragma unroll
        for (int mt = 0; mt < 4; mt++) {
            rm = fmaxf(rm, fmaxf(fmaxf(sc4[mt][0], sc4[mt][1]),
                                 fmaxf(sc4[mt][2], sc4[mt][3])));
        }
        rm = fmaxf(rm, __shfl_xor(rm, 16));
        rm = fmaxf(rm, __shfl_xor(rm, 32));
        float mn = fmaxf(m_run, rm);
        bool resc = (__ballot(mn > m_run) != 0ULL);
        float al = fexp2(m_run - mn);
        m_run = mn;
        if (resc) {
#pragma unroll
            for (int n = 0; n < 9; n++)
#pragma unroll
                for (int r = 0; r < 4; r++) oa[n][r] *= al;
        }

        // P = exp2(S - m), packed bf16 pairs: pku[mt*2+t] = keys(mt*16+qd*4+2t, +1)
        u32 pku[8];
#pragma unroll
        for (int mt = 0; mt < 4; mt++) {
#pragma unroll
            for (int t = 0; t < 2; t++)
                pku[mt * 2 + t] = pack_bf16_trunc(fexp2(sc4[mt][2 * t] - mn),
                                                  fexp2(sc4[mt][2 * t + 1] - mn));
        }

        // O^T += V^T * P^T  (B-frag of P^T built by register shuffle)
#pragma unroll
        for (int kc = 0; kc < 2; kc++) {
            union { u32 w[4]; bf16x8 v; } pb;
#pragma unroll
            for (int s = 0; s < 4; s++) {
                int srcl = ((2 * (qd & 1) + (s >> 1)) << 4) | ln;
                u32 a0 = (u32)__shfl((int)pku[4 * kc + (s & 1)], srcl);
                u32 a1 = (u32)__shfl((int)pku[4 * kc + 2 + (s & 1)], srcl);
                pb.w[s] = (qd & 2) ? a1 : a0;
            }
            const int cs = ((4 * kc + qd) ^ x7) * 8;
#pragma unroll
            for (int mt = 0; mt < 9; mt++) {
                bf16x8 vf = *(const bf16x8*)&Vs[mt * 16 + ln][cs];
                oa[mt] = __builtin_amdgcn_mfma_f32_16x16x32_bf16(vf, pb.v, oa[mt], 0, 0, 0);
            }
        }
        __syncthreads();
    }

    // l lives in quad 0, reg 0 of oa[8]; broadcast, normalize, store O[q][d]
    float l = __shfl(oa[8][0], ln);
    float linv = 1.0f / l;
    u16* op = O + ((size_t)b * Sz + qabs) * Dz + h * HDz;
#pragma unroll
    for (int mt = 0; mt < 8; mt++) {
        u32 w0 = pack_bf16_rn(oa[mt][0] * linv, oa[mt][1] * linv);
        u32 w1 = pack_bf16_rn(oa[mt][2] * linv, oa[mt][3] * linv);
        uint2 ww; ww.x = w0; ww.y = w1;
        *(uint2*)(op + mt * 16 + qd * 4) = ww;
    }
}

// ---------------------------------------------------------------------------
extern "C" void kernel_launch(void* const* d_in, const int* in_sizes, int n_in,
                              void* d_out, int out_size, void* d_ws, size_t ws_size,
                              hipStream_t stream) {
    const float* x  = (const float*)d_in[0];
    const float* Wq = (const float*)d_in[1];
    const float* Wk = (const float*)d_in[2];
    const float* Wv = (const float*)d_in[3];
    const float* Wo = (const float*)d_in[4];
    u16* ws  = (u16*)d_ws;

    u16* wt = ws;                       // 4 * 4,194,304 transposed bf16 weights (32 MB)
    u16* q  = ws + 16777216;            // [B,H,S,HD]
    u16* kk = q + 8388608;              // [B,H,S,HD]
    u16* v  = kk + 8388608;             // [B,H,HD,S]
    u16* xb = v + 8388608;              // bf16(x); reused as o after QKV gemm
    u16* o  = xb;

    cvt_f32_bf16<<<dim3(4096), 256, 0, stream>>>(x, xb);
    transpose_w<<<dim3(32, 32, 4), 256, 0, stream>>>(Wq, Wk, Wv, Wo, wt);
    gemm256_qkv<<<dim3(8, 16, 3), 512, 0, stream>>>(xb, wt, q);
    rope_kernel<<<dim3(32768), 256, 0, stream>>>(q, kk);
    flash_attn<<<dim3(1024), 256, 0, stream>>>(q, kk, v, o);
    gemm_bt<0><<<dim3(16, 32, 1), 256, 0, stream>>>(o, wt + 3 * 4194304, (float*)d_out);
}

// Round 4
// 396.191 us; speedup vs baseline: 1.1498x; 1.1498x over previous
//
#include <hip/hip_runtime.h>
#include <hip/hip_bf16.h>
#include <math.h>

typedef unsigned short u16;
typedef unsigned int u32;

#define Bz 2
#define Sz 2048
#define Dz 2048
#define Hz 16
#define HDz 128
#define Mz 4096

typedef __bf16 bf16x8 __attribute__((ext_vector_type(8)));
typedef float f32x4 __attribute__((ext_vector_type(4)));

__device__ __forceinline__ float bf2f(u16 h) {
    union { u32 u; float f; } x; x.u = ((u32)h) << 16; return x.f;
}
__device__ __forceinline__ u16 f2bf(float f) {
    union { float f; u32 u; } x; x.f = f;
    u32 u = x.u;
    return (u16)((u + 0x7FFFu + ((u >> 16) & 1u)) >> 16);
}
// truncating pack (hot path; P in [0,1], bias cancels via consistent l)
__device__ __forceinline__ u32 pack_bf16_trunc(float lo, float hi) {
    union { float f; u32 u; } a, b; a.f = lo; b.f = hi;
    return (a.u >> 16) | (b.u & 0xFFFF0000u);
}
__device__ __forceinline__ u32 pack_bf16_rn(float lo, float hi) {
    return (u32)f2bf(lo) | ((u32)f2bf(hi) << 16);
}
__device__ __forceinline__ float fexp2(float x) {
#if __has_builtin(__builtin_amdgcn_exp2f)
    return __builtin_amdgcn_exp2f(x);
#else
    return exp2f(x);
#endif
}
// async global->LDS, 16B per lane; lds dest = uniform base + lane*16
__device__ __forceinline__ void gl_lds16(const void* g, void* l) {
    __builtin_amdgcn_global_load_lds(
        (const __attribute__((address_space(1))) void*)g,
        (__attribute__((address_space(3))) void*)l, 16, 0, 0);
}

// ---------------- fp32 -> bf16 convert (x) ---------------------------------
__global__ void cvt_f32_bf16(const float* __restrict__ src, u16* __restrict__ dst) {
    size_t i = (size_t)blockIdx.x * blockDim.x + threadIdx.x;  // one per 8 elems
    float4 a = ((const float4*)src)[2 * i];
    float4 b = ((const float4*)src)[2 * i + 1];
    u16 r[8] = {f2bf(a.x), f2bf(a.y), f2bf(a.z), f2bf(a.w),
                f2bf(b.x), f2bf(b.y), f2bf(b.z), f2bf(b.w)};
    *(uint4*)(dst + 8 * i) = *(const uint4*)r;
}

// ---------------- weight transpose+convert: Wt[n][k] = bf16(W[k][n]) -------
__global__ void transpose_w(const float* __restrict__ W0, const float* __restrict__ W1,
                            const float* __restrict__ W2, const float* __restrict__ W3,
                            u16* __restrict__ Wt) {
    __shared__ u16 t[64][65];
    const float* src = (blockIdx.z == 0) ? W0 : (blockIdx.z == 1) ? W1
                     : (blockIdx.z == 2) ? W2 : W3;
    u16* dst = Wt + (size_t)blockIdx.z * (Dz * Dz);
    int x = blockIdx.x * 64, y = blockIdx.y * 64;
    int c = threadIdx.x & 63, rb = (threadIdx.x >> 6) * 16;
#pragma unroll
    for (int i = 0; i < 16; i++) {
        int r = rb + i;
        t[r][c] = f2bf(src[(size_t)(y + r) * Dz + x + c]);
    }
    __syncthreads();
#pragma unroll
    for (int i = 0; i < 16; i++) {
        int r = rb + i;
        dst[(size_t)(x + r) * Dz + y + c] = t[c][r];
    }
}

// ---------------- GEMM: C = A[M,K](bf16) * Wt[N,K]^T(bf16), 128x128 tile ----
// global_load_lds staging + XOR-swizzled LDS (block cb of row r stored at
// cb ^ (r&7)) -> conflict-free ds_read_b128 fragment reads.
// MODE 0: fp32 row-major store. MODE 1: bf16 scatter (z=0/1 [B,H,S,HD]; z=2 [B,H,HD,S]).
// XCD-aware block swizzle (T1): grid (x,y) plane is 16x32 = 512 blocks;
// 512 % 8 == 0 so the simple bijective form applies. HW round-robins linear
// ids across the 8 XCDs; remap so XCD j owns contiguous work ids
// [j*64,(j+1)*64) = 4 consecutive A-panels (2 MB, L2-resident) instead of 32
// scattered ones -> A-panel refetch drops.
template <int MODE>
__global__ void gemm_bt(const u16* __restrict__ A, const u16* __restrict__ BtBase,
                        void* __restrict__ CBase) {
    const int z = blockIdx.z;
    const u16* Bt = BtBase + (size_t)z * (Dz * Dz);
    const int tid = threadIdx.x, lane = tid & 63, wave = tid >> 6;
    const int ln = lane & 15, qd = lane >> 4;
    // XCD swizzle over the 512-block (x,y) plane (assumes gridDim = (16,32,z))
    const int lid = blockIdx.y * 16 + blockIdx.x;
    const int wid = (lid & 7) * 64 + (lid >> 3);
    const int m0 = (wid >> 4) * 128, n0 = (wid & 15) * 128;

    __shared__ __align__(16) u16 As[128][64];
    __shared__ __align__(16) u16 Bs[128][64];

    f32x4 acc[4][4];
#pragma unroll
    for (int i = 0; i < 4; i++)
#pragma unroll
        for (int j = 0; j < 4; j++) acc[i][j] = (f32x4){0.f, 0.f, 0.f, 0.f};

    const int wm = (wave >> 1) * 64, wn = (wave & 1) * 64;
    const int lr8 = lane >> 3;                         // row-within-8 (= row&7)
    const int bgo = (((lane & 7) ^ lr8) * 8);          // swizzled u16 col offset
    const int x7 = ln & 7;

    for (int k0 = 0; k0 < Dz; k0 += 64) {
        const u16* ga = A  + (size_t)(m0 + wave * 32 + lr8) * Dz + k0 + bgo;
        const u16* gb = Bt + (size_t)(n0 + wave * 32 + lr8) * Dz + k0 + bgo;
#pragma unroll
        for (int i = 0; i < 4; i++) {
            gl_lds16(ga + (size_t)(8 * i) * Dz, &As[wave * 32 + 8 * i][0]);
            gl_lds16(gb + (size_t)(8 * i) * Dz, &Bs[wave * 32 + 8 * i][0]);
        }
        __syncthreads();
#pragma unroll
        for (int kc = 0; kc < 2; kc++) {
            bf16x8 af[4], bff[4];
            const int cs = ((4 * kc + qd) ^ x7) * 8;   // swizzled fragment col
#pragma unroll
            for (int i = 0; i < 4; i++) {
                af[i]  = *(const bf16x8*)&As[wm + i * 16 + ln][cs];
                bff[i] = *(const bf16x8*)&Bs[wn + i * 16 + ln][cs];
            }
#pragma unroll
            for (int i = 0; i < 4; i++)
#pragma unroll
                for (int j = 0; j < 4; j++)
                    acc[i][j] = __builtin_amdgcn_mfma_f32_16x16x32_bf16(
                        af[i], bff[j], acc[i][j], 0, 0, 0);
        }
        __syncthreads();
    }

#pragma unroll
    for (int i = 0; i < 4; i++) {
#pragma unroll
        for (int j = 0; j < 4; j++) {
#pragma unroll
            for (int r = 0; r < 4; r++) {
                int row = m0 + wm + i * 16 + qd * 4 + r;
                int col = n0 + wn + j * 16 + ln;
                if (MODE == 0) {
                    ((float*)CBase)[(size_t)row * Dz + col] = acc[i][j][r];
                } else {
                    u16* C = (u16*)CBase + (size_t)z * ((size_t)Mz * Dz);
                    u16 hv = f2bf(acc[i][j][r]);
                    int bb = row >> 11, ss = row & 2047;
                    int hh = col >> 7, hd = col & 127;
                    if (z == 2)
                        C[((size_t)(bb * Hz + hh) * HDz + hd) * Sz + ss] = hv;
                    else
                        C[((size_t)(bb * Hz + hh) * Sz + ss) * HDz + hd] = hv;
                }
            }
        }
    }
}

// ---------------- RoPE in place; Q additionally scaled by SCALE*log2e ------
__global__ void rope_kernel(u16* __restrict__ Q, u16* __restrict__ Kk) {
    u32 idx = blockIdx.x * blockDim.x + threadIdx.x;   // 2^23 threads
    int isK = (idx >> 22) & 1;
    u16* T = isK ? Kk : Q;
    u32 p = idx & 0x3FFFFFu;                           // pair index within tensor
    int j = p & 63;
    int s = (p >> 6) & 2047;
    size_t base = (size_t)(p >> 6) * HDz + 2 * j;
    u32 u = *(u32*)(T + base);
    float x0 = bf2f((u16)(u & 0xFFFFu));
    float x1 = bf2f((u16)(u >> 16));
    int i0 = (2 * j) & 63;
    const float LG = 0.20762050593046017f;             // log2(10000)/64
    float f0 = exp2f(-LG * (float)i0);
    float f1 = exp2f(-LG * (float)(i0 + 1));
    float th0 = (float)s * f0, th1 = (float)s * f1;
    float s0, c0, s1, c1;
    sincosf(th0, &s0, &c0);
    sincosf(th1, &s1, &c1);
    // 1/sqrt(HD) * log2(e), folded into Q so flash works in exp2 domain
    float scl = isK ? 1.0f : 0.12751771218027603f;
    float y0 = (x0 * c0 - x1 * s0) * scl;
    float y1 = (x1 * c1 + x0 * s1) * scl;
    u32 outw = (u32)f2bf(y0) | ((u32)f2bf(y1) << 16);
    *(u32*)(T + base) = outw;
}

// ---------------- causal flash attention, S^T formulation ------------------
// Q,K: [B,H,S,HD] (Q pre-scaled); Vt: [B,H,HD,S]; O: [B,S,H*HD].
// Block: 4 waves x 16 q-cols = 64 q; k-tiles of 64 keys.
// S^T = K*Q^T; O^T = V^T*P^T; l via ones-row of V. XOR-swizzled Ks/Vs.
__global__ __launch_bounds__(256, 4)
void flash_attn(const u16* __restrict__ Q, const u16* __restrict__ Kk,
                const u16* __restrict__ Vt, u16* __restrict__ O) {
    const int tid = threadIdx.x, lane = tid & 63, wave = tid >> 6;
    const int ln = lane & 15, qd = lane >> 4;
    const int bh = blockIdx.x & 31;
    const int qt = 31 - (blockIdx.x >> 5);             // heavy q-tiles first
    const int b = bh >> 4, h = bh & 15;
    const int q0 = qt * 64;
    const u16* Qh = Q  + (size_t)bh * Sz * HDz;
    const u16* Kh = Kk + (size_t)bh * Sz * HDz;
    const u16* Vh = Vt + (size_t)bh * HDz * Sz;

    __shared__ __align__(16) u16 Ks[64][128];          // [key][d], swizzled blocks
    __shared__ __align__(16) u16 Vs[144][64];          // [d][key], swizzled; rows 128..143 ones-block

    // init ones-row block of Vs (row-uniform -> swizzle-invariant)
    for (int idx = tid; idx < 16 * 64; idx += 256) {
        int rr = idx >> 6, cc = idx & 63;
        Vs[128 + rr][cc] = (rr == 0) ? (u16)0x3F80 : (u16)0;
    }

    // Q B-fragments, direct from global (q = ln column, k = qd*8 + j)
    const int qabs = q0 + wave * 16 + ln;
    bf16x8 qf[4];
#pragma unroll
    for (int kc = 0; kc < 4; kc++) {
        uint4 t = *(const uint4*)(Qh + (size_t)qabs * HDz + kc * 32 + qd * 8);
        qf[kc] = *(const bf16x8*)&t;
    }

    float m_run = -INFINITY;
    f32x4 oa[9];                                       // O^T[d][q=ln]; oa[8] = l row
#pragma unroll
    for (int n = 0; n < 9; n++) oa[n] = (f32x4){0.f, 0.f, 0.f, 0.f};

    const int x7 = ln & 7;
    const int l4 = lane >> 4, c16 = lane & 15;         // K staging map
    const int lr8 = lane >> 3;                         // V staging map
    const int bgv = ((lane & 7) ^ lr8) * 8;

    for (int k0 = 0; k0 <= q0; k0 += 64) {
        // async stage K (64x128) and V (128x64), swizzled
        {
#pragma unroll
            for (int i = 0; i < 4; i++) {
                int rw = 4 * (i & 1) + l4;             // (row & 7)
                const u16* gk = Kh + (size_t)(k0 + 16 * wave + 4 * i + l4) * HDz
                                   + ((c16 ^ rw) * 8);
                gl_lds16(gk, &Ks[16 * wave + 4 * i][0]);
            }
            const u16* gv = Vh + (size_t)(32 * wave + lr8) * Sz + k0 + bgv;
#pragma unroll
            for (int i = 0; i < 4; i++)
                gl_lds16(gv + (size_t)(8 * i) * Sz, &Vs[32 * wave + 8 * i][0]);
        }
        __syncthreads();

        // S^T tile: C[key=mt*16+qd*4+r][q=ln]
        f32x4 sc4[4];
#pragma unroll
        for (int mt = 0; mt < 4; mt++) sc4[mt] = (f32x4){0.f, 0.f, 0.f, 0.f};
#pragma unroll
        for (int kc = 0; kc < 4; kc++) {
            const int cs = ((4 * kc + qd) ^ x7) * 8;
#pragma unroll
            for (int mt = 0; mt < 4; mt++) {
                bf16x8 kf = *(const bf16x8*)&Ks[mt * 16 + ln][cs];
                sc4[mt] = __builtin_amdgcn_mfma_f32_16x16x32_bf16(kf, qf[kc], sc4[mt], 0, 0, 0);
            }
        }
        if (k0 == q0) {                                // causal mask, diagonal tile only
#pragma unroll
            for (int mt = 0; mt < 4; mt++)
#pragma unroll
                for (int r = 0; r < 4; r++)
                    if (mt * 16 + qd * 4 + r > 16 * wave + ln) sc4[mt][r] = -3e38f;
        }

        // row max: in-register + cross-quad
        float rm = -3e38f;
#pragma unroll
        for (int mt = 0; mt < 4; mt++) {
            rm = fmaxf(rm, fmaxf(fmaxf(sc4[mt][0], sc4[mt][1]),
                                 fmaxf(sc4[mt][2], sc4[mt][3])));
        }
        rm = fmaxf(rm, __shfl_xor(rm, 16));
        rm = fmaxf(rm, __shfl_xor(rm, 32));
        float mn = fmaxf(m_run, rm);
        bool resc = (__ballot(mn > m_run) != 0ULL);
        float al = fexp2(m_run - mn);
        m_run = mn;
        if (resc) {
#pragma unroll
            for (int n = 0; n < 9; n++)
#pragma unroll
                for (int r = 0; r < 4; r++) oa[n][r] *= al;
        }

        // P = exp2(S - m), packed bf16 pairs: pku[mt*2+t] = keys(mt*16+qd*4+2t, +1)
        u32 pku[8];
#pragma unroll
        for (int mt = 0; mt < 4; mt++) {
#pragma unroll
            for (int t = 0; t < 2; t++)
                pku[mt * 2 + t] = pack_bf16_trunc(fexp2(sc4[mt][2 * t] - mn),
                                                  fexp2(sc4[mt][2 * t + 1] - mn));
        }

        // O^T += V^T * P^T  (B-frag of P^T built by register shuffle)
#pragma unroll
        for (int kc = 0; kc < 2; kc++) {
            union { u32 w[4]; bf16x8 v; } pb;
#pragma unroll
            for (int s = 0; s < 4; s++) {
                int srcl = ((2 * (qd & 1) + (s >> 1)) << 4) | ln;
                u32 a0 = (u32)__shfl((int)pku[4 * kc + (s & 1)], srcl);
                u32 a1 = (u32)__shfl((int)pku[4 * kc + 2 + (s & 1)], srcl);
                pb.w[s] = (qd & 2) ? a1 : a0;
            }
            const int cs = ((4 * kc + qd) ^ x7) * 8;
#pragma unroll
            for (int mt = 0; mt < 9; mt++) {
                bf16x8 vf = *(const bf16x8*)&Vs[mt * 16 + ln][cs];
                oa[mt] = __builtin_amdgcn_mfma_f32_16x16x32_bf16(vf, pb.v, oa[mt], 0, 0, 0);
            }
        }
        __syncthreads();
    }

    // l lives in quad 0, reg 0 of oa[8]; broadcast, normalize, store O[q][d]
    float l = __shfl(oa[8][0], ln);
    float linv = 1.0f / l;
    u16* op = O + ((size_t)b * Sz + qabs) * Dz + h * HDz;
#pragma unroll
    for (int mt = 0; mt < 8; mt++) {
        u32 w0 = pack_bf16_rn(oa[mt][0] * linv, oa[mt][1] * linv);
        u32 w1 = pack_bf16_rn(oa[mt][2] * linv, oa[mt][3] * linv);
        uint2 ww; ww.x = w0; ww.y = w1;
        *(uint2*)(op + mt * 16 + qd * 4) = ww;
    }
}

// ---------------------------------------------------------------------------
extern "C" void kernel_launch(void* const* d_in, const int* in_sizes, int n_in,
                              void* d_out, int out_size, void* d_ws, size_t ws_size,
                              hipStream_t stream) {
    const float* x  = (const float*)d_in[0];
    const float* Wq = (const float*)d_in[1];
    const float* Wk = (const float*)d_in[2];
    const float* Wv = (const float*)d_in[3];
    const float* Wo = (const float*)d_in[4];
    u16* ws  = (u16*)d_ws;

    u16* wt = ws;                       // 4 * 4,194,304 transposed bf16 weights (32 MB)
    u16* q  = ws + 16777216;            // [B,H,S,HD]
    u16* kk = q + 8388608;              // [B,H,S,HD]
    u16* v  = kk + 8388608;             // [B,H,HD,S]
    u16* xb = v + 8388608;              // bf16(x); reused as o after gemm<1>
    u16* o  = xb;

    cvt_f32_bf16<<<dim3(4096), 256, 0, stream>>>(x, xb);
    transpose_w<<<dim3(32, 32, 4), 256, 0, stream>>>(Wq, Wk, Wv, Wo, wt);
    gemm_bt<1><<<dim3(16, 32, 3), 256, 0, stream>>>(xb, wt, q);
    rope_kernel<<<dim3(32768), 256, 0, stream>>>(q, kk);
    flash_attn<<<dim3(1024), 256, 0, stream>>>(q, kk, v, o);
    gemm_bt<0><<<dim3(16, 32, 1), 256, 0, stream>>>(o, wt + 3 * 4194304, (float*)d_out);
}

// Round 6
// 393.248 us; speedup vs baseline: 1.1584x; 1.0075x over previous
//
#include <hip/hip_runtime.h>
#include <hip/hip_bf16.h>
#include <math.h>

typedef unsigned short u16;
typedef unsigned int u32;

#define Bz 2
#define Sz 2048
#define Dz 2048
#define Hz 16
#define HDz 128
#define Mz 4096

typedef __bf16 bf16x8 __attribute__((ext_vector_type(8)));
typedef float f32x4 __attribute__((ext_vector_type(4)));

__device__ __forceinline__ float bf2f(u16 h) {
    union { u32 u; float f; } x; x.u = ((u32)h) << 16; return x.f;
}
__device__ __forceinline__ u16 f2bf(float f) {
    union { float f; u32 u; } x; x.f = f;
    u32 u = x.u;
    return (u16)((u + 0x7FFFu + ((u >> 16) & 1u)) >> 16);
}
// truncating pack (hot path; P in [0,1], bias cancels via consistent l)
__device__ __forceinline__ u32 pack_bf16_trunc(float lo, float hi) {
    union { float f; u32 u; } a, b; a.f = lo; b.f = hi;
    return (a.u >> 16) | (b.u & 0xFFFF0000u);
}
__device__ __forceinline__ u32 pack_bf16_rn(float lo, float hi) {
    return (u32)f2bf(lo) | ((u32)f2bf(hi) << 16);
}
__device__ __forceinline__ float fexp2(float x) {
#if __has_builtin(__builtin_amdgcn_exp2f)
    return __builtin_amdgcn_exp2f(x);
#else
    return exp2f(x);
#endif
}
// async global->LDS, 16B per lane; lds dest = uniform base + lane*16
__device__ __forceinline__ void gl_lds16(const void* g, void* l) {
    __builtin_amdgcn_global_load_lds(
        (const __attribute__((address_space(1))) void*)g,
        (__attribute__((address_space(3))) void*)l, 16, 0, 0);
}

// ---------------- fp32 -> bf16 convert (x) ---------------------------------
__global__ void cvt_f32_bf16(const float* __restrict__ src, u16* __restrict__ dst) {
    size_t i = (size_t)blockIdx.x * blockDim.x + threadIdx.x;  // one per 8 elems
    float4 a = ((const float4*)src)[2 * i];
    float4 b = ((const float4*)src)[2 * i + 1];
    u16 r[8] = {f2bf(a.x), f2bf(a.y), f2bf(a.z), f2bf(a.w),
                f2bf(b.x), f2bf(b.y), f2bf(b.z), f2bf(b.w)};
    *(uint4*)(dst + 8 * i) = *(const uint4*)r;
}

// ---------------- weight transpose+convert: Wt[n][k] = bf16(W[k][n]) -------
__global__ void transpose_w(const float* __restrict__ W0, const float* __restrict__ W1,
                            const float* __restrict__ W2, const float* __restrict__ W3,
                            u16* __restrict__ Wt) {
    __shared__ u16 t[64][65];
    const float* src = (blockIdx.z == 0) ? W0 : (blockIdx.z == 1) ? W1
                     : (blockIdx.z == 2) ? W2 : W3;
    u16* dst = Wt + (size_t)blockIdx.z * (Dz * Dz);
    int x = blockIdx.x * 64, y = blockIdx.y * 64;
    int c = threadIdx.x & 63, rb = (threadIdx.x >> 6) * 16;
#pragma unroll
    for (int i = 0; i < 16; i++) {
        int r = rb + i;
        t[r][c] = f2bf(src[(size_t)(y + r) * Dz + x + c]);
    }
    __syncthreads();
#pragma unroll
    for (int i = 0; i < 16; i++) {
        int r = rb + i;
        dst[(size_t)(x + r) * Dz + y + c] = t[c][r];
    }
}

// ---------------- GEMM: C = A[M,K](bf16) * Wt[N,K]^T(bf16), 128x128 tile ----
// global_load_lds staging + XOR-swizzled LDS (block cb of row r stored at
// cb ^ (r&7)) -> conflict-free ds_read_b128 fragment reads.
// MODE 0: fp32 row-major store. MODE 1: bf16 scatter (z=0/1 [B,H,S,HD] with
// FUSED RoPE applied to the fp32 accumulator; z=2 [B,H,HD,S], no RoPE).
// XCD-aware block swizzle (T1): 512-block (x,y) plane, 512 % 8 == 0 ->
// bijective simple form; each XCD owns 64 contiguous work ids = 4 A-panels
// (2 MB, L2-resident). Verified r4: FETCH 198->147 MB, dur neutral
// (structure-bound at ~930 TF, the m97 ceiling).
template <int MODE>
__global__ void gemm_bt(const u16* __restrict__ A, const u16* __restrict__ BtBase,
                        void* __restrict__ CBase) {
    const int z = blockIdx.z;
    const u16* Bt = BtBase + (size_t)z * (Dz * Dz);
    const int tid = threadIdx.x, lane = tid & 63, wave = tid >> 6;
    const int ln = lane & 15, qd = lane >> 4;
    // XCD swizzle over the 512-block (x,y) plane (assumes gridDim = (16,32,z))
    const int lid = blockIdx.y * 16 + blockIdx.x;
    const int wid = (lid & 7) * 64 + (lid >> 3);
    const int m0 = (wid >> 4) * 128, n0 = (wid & 15) * 128;

    __shared__ __align__(16) u16 As[128][64];
    __shared__ __align__(16) u16 Bs[128][64];

    f32x4 acc[4][4];
#pragma unroll
    for (int i = 0; i < 4; i++)
#pragma unroll
        for (int j = 0; j < 4; j++) acc[i][j] = (f32x4){0.f, 0.f, 0.f, 0.f};

    const int wm = (wave >> 1) * 64, wn = (wave & 1) * 64;
    const int lr8 = lane >> 3;                         // row-within-8 (= row&7)
    const int bgo = (((lane & 7) ^ lr8) * 8);          // swizzled u16 col offset
    const int x7 = ln & 7;

    for (int k0 = 0; k0 < Dz; k0 += 64) {
        const u16* ga = A  + (size_t)(m0 + wave * 32 + lr8) * Dz + k0 + bgo;
        const u16* gb = Bt + (size_t)(n0 + wave * 32 + lr8) * Dz + k0 + bgo;
#pragma unroll
        for (int i = 0; i < 4; i++) {
            gl_lds16(ga + (size_t)(8 * i) * Dz, &As[wave * 32 + 8 * i][0]);
            gl_lds16(gb + (size_t)(8 * i) * Dz, &Bs[wave * 32 + 8 * i][0]);
        }
        __syncthreads();
#pragma unroll
        for (int kc = 0; kc < 2; kc++) {
            bf16x8 af[4], bff[4];
            const int cs = ((4 * kc + qd) ^ x7) * 8;   // swizzled fragment col
#pragma unroll
            for (int i = 0; i < 4; i++) {
                af[i]  = *(const bf16x8*)&As[wm + i * 16 + ln][cs];
                bff[i] = *(const bf16x8*)&Bs[wn + i * 16 + ln][cs];
            }
#pragma unroll
            for (int i = 0; i < 4; i++)
#pragma unroll
                for (int j = 0; j < 4; j++)
                    acc[i][j] = __builtin_amdgcn_mfma_f32_16x16x32_bf16(
                        af[i], bff[j], acc[i][j], 0, 0, 0);
        }
        __syncthreads();
    }

#pragma unroll
    for (int i = 0; i < 4; i++) {
#pragma unroll
        for (int j = 0; j < 4; j++) {
#pragma unroll
            for (int r = 0; r < 4; r++) {
                int row = m0 + wm + i * 16 + qd * 4 + r;
                int col = n0 + wn + j * 16 + ln;
                if (MODE == 0) {
                    ((float*)CBase)[(size_t)row * Dz + col] = acc[i][j][r];
                } else {
                    u16* C = (u16*)CBase + (size_t)z * ((size_t)Mz * Dz);
                    float v = acc[i][j][r];
                    int bb = row >> 11, ss = row & 2047;
                    int hh = col >> 7, hd = col & 127;
                    if (z == 2) {
                        C[((size_t)(bb * Hz + hh) * HDz + hd) * Sz + ss] = f2bf(v);
                    } else {
                        // fused RoPE: partner x[hd^1] lives in adjacent lane
                        // (col = ... + ln). rotate_half: even hd -> -x[hd+1],
                        // odd hd -> +x[hd-1]. theta = ss*10000^(-(hd&63)/64).
                        float partner = __shfl_xor(v, 1);
                        const float LG = 0.20762050593046017f; // log2(10000)/64
                        float th = (float)ss * fexp2(-LG * (float)(hd & 63));
                        float sn, cn;
                        sincosf(th, &sn, &cn);
                        float rot = (hd & 1) ? partner : -partner;
                        float y = v * cn + rot * sn;
                        // 1/sqrt(HD)*log2(e) folded into Q (exp2-domain flash)
                        if (z == 0) y *= 0.12751771218027603f;
                        C[((size_t)(bb * Hz + hh) * Sz + ss) * HDz + hd] = f2bf(y);
                    }
                }
            }
        }
    }
}

// ---------------- causal flash attention, S^T formulation ------------------
// Q,K: [B,H,S,HD] (Q pre-scaled, RoPE fused upstream); Vt: [B,H,HD,S];
// O: [B,S,H*HD]. Block: 4 waves x 16 q-cols = 64 q; k-tiles of 64 keys.
// S^T = K*Q^T; O^T = V^T*P^T; l via ones-row of V. XOR-swizzled Ks/Vs.
// Load-balanced qt map: co-resident blocks {bid, bid+256, +512, +768} share a
// CU (bid mod 256 -> CU under round-robin dispatch) and get qt =
// {m, 31-m, 8+m, 23-m} (bijective over 0..31): per-CU key-sum is the constant
// 66 tiles, vs 80-4m for the old qt=31-(bid>>5) (21% tail imbalance).
// bh = bid&31 unchanged -> per-XCD K/V L2 locality preserved.
__global__ __launch_bounds__(256, 4)
void flash_attn(const u16* __restrict__ Q, const u16* __restrict__ Kk,
                const u16* __restrict__ Vt, u16* __restrict__ O) {
    const int tid = threadIdx.x, lane = tid & 63, wave = tid >> 6;
    const int ln = lane & 15, qd = lane >> 4;
    const int bh = blockIdx.x & 31;
    const int g = blockIdx.x >> 5;                     // 0..31
    const int gm = g & 7, gj = g >> 3;
    const int qt = (gj == 0) ? gm : (gj == 1) ? 31 - gm
                 : (gj == 2) ? 8 + gm : 23 - gm;
    const int b = bh >> 4, h = bh & 15;
    const int q0 = qt * 64;
    const u16* Qh = Q  + (size_t)bh * Sz * HDz;
    const u16* Kh = Kk + (size_t)bh * Sz * HDz;
    const u16* Vh = Vt + (size_t)bh * HDz * Sz;

    __shared__ __align__(16) u16 Ks[64][128];          // [key][d], swizzled blocks
    __shared__ __align__(16) u16 Vs[144][64];          // [d][key], swizzled; rows 128..143 ones-block

    // init ones-row block of Vs (row-uniform -> swizzle-invariant)
    for (int idx = tid; idx < 16 * 64; idx += 256) {
        int rr = idx >> 6, cc = idx & 63;
        Vs[128 + rr][cc] = (rr == 0) ? (u16)0x3F80 : (u16)0;
    }

    // Q B-fragments, direct from global (q = ln column, k = qd*8 + j)
    const int qabs = q0 + wave * 16 + ln;
    bf16x8 qf[4];
#pragma unroll
    for (int kc = 0; kc < 4; kc++) {
        uint4 t = *(const uint4*)(Qh + (size_t)qabs * HDz + kc * 32 + qd * 8);
        qf[kc] = *(const bf16x8*)&t;
    }

    float m_run = -INFINITY;
    f32x4 oa[9];                                       // O^T[d][q=ln]; oa[8] = l row
#pragma unroll
    for (int n = 0; n < 9; n++) oa[n] = (f32x4){0.f, 0.f, 0.f, 0.f};

    const int x7 = ln & 7;
    const int l4 = lane >> 4, c16 = lane & 15;         // K staging map
    const int lr8 = lane >> 3;                         // V staging map
    const int bgv = ((lane & 7) ^ lr8) * 8;

    for (int k0 = 0; k0 <= q0; k0 += 64) {
        // async stage K (64x128) and V (128x64), swizzled
        {
#pragma unroll
            for (int i = 0; i < 4; i++) {
                int rw = 4 * (i & 1) + l4;             // (row & 7)
                const u16* gk = Kh + (size_t)(k0 + 16 * wave + 4 * i + l4) * HDz
                                   + ((c16 ^ rw) * 8);
                gl_lds16(gk, &Ks[16 * wave + 4 * i][0]);
            }
            const u16* gv = Vh + (size_t)(32 * wave + lr8) * Sz + k0 + bgv;
#pragma unroll
            for (int i = 0; i < 4; i++)
                gl_lds16(gv + (size_t)(8 * i) * Sz, &Vs[32 * wave + 8 * i][0]);
        }
        __syncthreads();

        // S^T tile: C[key=mt*16+qd*4+r][q=ln]
        f32x4 sc4[4];
#pragma unroll
        for (int mt = 0; mt < 4; mt++) sc4[mt] = (f32x4){0.f, 0.f, 0.f, 0.f};
#pragma unroll
        for (int kc = 0; kc < 4; kc++) {
            const int cs = ((4 * kc + qd) ^ x7) * 8;
#pragma unroll
            for (int mt = 0; mt < 4; mt++) {
                bf16x8 kf = *(const bf16x8*)&Ks[mt * 16 + ln][cs];
                sc4[mt] = __builtin_amdgcn_mfma_f32_16x16x32_bf16(kf, qf[kc], sc4[mt], 0, 0, 0);
            }
        }
        if (k0 == q0) {                                // causal mask, diagonal tile only
#pragma unroll
            for (int mt = 0; mt < 4; mt++)
#pragma unroll
                for (int r = 0; r < 4; r++)
                    if (mt * 16 + qd * 4 + r > 16 * wave + ln) sc4[mt][r] = -3e38f;
        }

        // row max: in-register + cross-quad
        float rm = -3e38f;
#pragma unroll
        for (int mt = 0; mt < 4; mt++) {
            rm = fmaxf(rm, fmaxf(fmaxf(sc4[mt][0], sc4[mt][1]),
                                 fmaxf(sc4[mt][2], sc4[mt][3])));
        }
        rm = fmaxf(rm, __shfl_xor(rm, 16));
        rm = fmaxf(rm, __shfl_xor(rm, 32));
        float mn = fmaxf(m_run, rm);
        bool resc = (__ballot(mn > m_run) != 0ULL);
        float al = fexp2(m_run - mn);
        m_run = mn;
        if (resc) {
#pragma unroll
            for (int n = 0; n < 9; n++)
#pragma unroll
                for (int r = 0; r < 4; r++) oa[n][r] *= al;
        }

        // P = exp2(S - m), packed bf16 pairs: pku[mt*2+t] = keys(mt*16+qd*4+2t, +1)
        u32 pku[8];
#pragma unroll
        for (int mt = 0; mt < 4; mt++) {
#pragma unroll
            for (int t = 0; t < 2; t++)
                pku[mt * 2 + t] = pack_bf16_trunc(fexp2(sc4[mt][2 * t] - mn),
                                                  fexp2(sc4[mt][2 * t + 1] - mn));
        }

        // O^T += V^T * P^T  (B-frag of P^T built by register shuffle)
#pragma unroll
        for (int kc = 0; kc < 2; kc++) {
            union { u32 w[4]; bf16x8 v; } pb;
#pragma unroll
            for (int s = 0; s < 4; s++) {
                int srcl = ((2 * (qd & 1) + (s >> 1)) << 4) | ln;
                u32 a0 = (u32)__shfl((int)pku[4 * kc + (s & 1)], srcl);
                u32 a1 = (u32)__shfl((int)pku[4 * kc + 2 + (s & 1)], srcl);
                pb.w[s] = (qd & 2) ? a1 : a0;
            }
            const int cs = ((4 * kc + qd) ^ x7) * 8;
#pragma unroll
            for (int mt = 0; mt < 9; mt++) {
                bf16x8 vf = *(const bf16x8*)&Vs[mt * 16 + ln][cs];
                oa[mt] = __builtin_amdgcn_mfma_f32_16x16x32_bf16(vf, pb.v, oa[mt], 0, 0, 0);
            }
        }
        __syncthreads();
    }

    // l lives in quad 0, reg 0 of oa[8]; broadcast, normalize, store O[q][d]
    float l = __shfl(oa[8][0], ln);
    float linv = 1.0f / l;
    u16* op = O + ((size_t)b * Sz + qabs) * Dz + h * HDz;
#pragma unroll
    for (int mt = 0; mt < 8; mt++) {
        u32 w0 = pack_bf16_rn(oa[mt][0] * linv, oa[mt][1] * linv);
        u32 w1 = pack_bf16_rn(oa[mt][2] * linv, oa[mt][3] * linv);
        uint2 ww; ww.x = w0; ww.y = w1;
        *(uint2*)(op + mt * 16 + qd * 4) = ww;
    }
}

// ---------------------------------------------------------------------------
extern "C" void kernel_launch(void* const* d_in, const int* in_sizes, int n_in,
                              void* d_out, int out_size, void* d_ws, size_t ws_size,
                              hipStream_t stream) {
    const float* x  = (const float*)d_in[0];
    const float* Wq = (const float*)d_in[1];
    const float* Wk = (const float*)d_in[2];
    const float* Wv = (const float*)d_in[3];
    const float* Wo = (const float*)d_in[4];
    u16* ws  = (u16*)d_ws;

    u16* wt = ws;                       // 4 * 4,194,304 transposed bf16 weights (32 MB)
    u16* q  = ws + 16777216;            // [B,H,S,HD] (RoPE+scale fused in gemm)
    u16* kk = q + 8388608;              // [B,H,S,HD] (RoPE fused in gemm)
    u16* v  = kk + 8388608;             // [B,H,HD,S]
    u16* xb = v + 8388608;              // bf16(x); reused as o after gemm<1>
    u16* o  = xb;

    cvt_f32_bf16<<<dim3(4096), 256, 0, stream>>>(x, xb);
    transpose_w<<<dim3(32, 32, 4), 256, 0, stream>>>(Wq, Wk, Wv, Wo, wt);
    gemm_bt<1><<<dim3(16, 32, 3), 256, 0, stream>>>(xb, wt, q);
    flash_attn<<<dim3(1024), 256, 0, stream>>>(q, kk, v, o);
    gemm_bt<0><<<dim3(16, 32, 1), 256, 0, stream>>>(o, wt + 3 * 4194304, (float*)d_out);
}

// Round 7
// 365.575 us; speedup vs baseline: 1.2461x; 1.0757x over previous
//
#include <hip/hip_runtime.h>
#include <hip/hip_bf16.h>
#include <math.h>

typedef unsigned short u16;
typedef unsigned int u32;

#define Bz 2
#define Sz 2048
#define Dz 2048
#define Hz 16
#define HDz 128
#define Mz 4096

typedef __bf16 bf16x8 __attribute__((ext_vector_type(8)));
typedef float f32x4 __attribute__((ext_vector_type(4)));

__device__ __forceinline__ float bf2f(u16 h) {
    union { u32 u; float f; } x; x.u = ((u32)h) << 16; return x.f;
}
__device__ __forceinline__ u16 f2bf(float f) {
    union { float f; u32 u; } x; x.f = f;
    u32 u = x.u;
    return (u16)((u + 0x7FFFu + ((u >> 16) & 1u)) >> 16);
}
// truncating pack (hot path; P in [0,1], bias cancels via consistent l)
__device__ __forceinline__ u32 pack_bf16_trunc(float lo, float hi) {
    union { float f; u32 u; } a, b; a.f = lo; b.f = hi;
    return (a.u >> 16) | (b.u & 0xFFFF0000u);
}
__device__ __forceinline__ u32 pack_bf16_rn(float lo, float hi) {
    return (u32)f2bf(lo) | ((u32)f2bf(hi) << 16);
}
__device__ __forceinline__ float fexp2(float x) {
#if __has_builtin(__builtin_amdgcn_exp2f)
    return __builtin_amdgcn_exp2f(x);
#else
    return exp2f(x);
#endif
}
// sin/cos of (2*pi*tr), tr in revolutions — hardware v_sin/v_cos after v_fract
__device__ __forceinline__ void sincos_rev(float tr, float* sn, float* cn) {
#if __has_builtin(__builtin_amdgcn_fractf) && __has_builtin(__builtin_amdgcn_sinf) && __has_builtin(__builtin_amdgcn_cosf)
    float fu = __builtin_amdgcn_fractf(tr);
    *sn = __builtin_amdgcn_sinf(fu);
    *cn = __builtin_amdgcn_cosf(fu);
#else
    sincosf(tr * 6.283185307179586f, sn, cn);
#endif
}
// async global->LDS, 16B per lane; lds dest = uniform base + lane*16
__device__ __forceinline__ void gl_lds16(const void* g, void* l) {
    __builtin_amdgcn_global_load_lds(
        (const __attribute__((address_space(1))) void*)g,
        (__attribute__((address_space(3))) void*)l, 16, 0, 0);
}

// ---------------- fp32 -> bf16 convert (x) ---------------------------------
__global__ void cvt_f32_bf16(const float* __restrict__ src, u16* __restrict__ dst) {
    size_t i = (size_t)blockIdx.x * blockDim.x + threadIdx.x;  // one per 8 elems
    float4 a = ((const float4*)src)[2 * i];
    float4 b = ((const float4*)src)[2 * i + 1];
    u16 r[8] = {f2bf(a.x), f2bf(a.y), f2bf(a.z), f2bf(a.w),
                f2bf(b.x), f2bf(b.y), f2bf(b.z), f2bf(b.w)};
    *(uint4*)(dst + 8 * i) = *(const uint4*)r;
}

// ---------------- weight transpose+convert: Wt[n][k] = bf16(W[k][n]) -------
// float4 loads (16B/lane), u32-paired bf16 stores (4B/lane).
__global__ void transpose_w(const float* __restrict__ W0, const float* __restrict__ W1,
                            const float* __restrict__ W2, const float* __restrict__ W3,
                            u16* __restrict__ Wt) {
    __shared__ u16 t[64][65];
    const float* src = (blockIdx.z == 0) ? W0 : (blockIdx.z == 1) ? W1
                     : (blockIdx.z == 2) ? W2 : W3;
    u16* dst = Wt + (size_t)blockIdx.z * (Dz * Dz);
    int x = blockIdx.x * 64, y = blockIdx.y * 64;
    // load: 4 consecutive source cols (float4) x 4 rows per thread
    {
        int c4 = (threadIdx.x & 15) * 4, r0 = (threadIdx.x >> 4) * 4;
#pragma unroll
        for (int i = 0; i < 4; i++) {
            int r = r0 + i;
            float4 v = *(const float4*)&src[(size_t)(y + r) * Dz + x + c4];
            t[r][c4 + 0] = f2bf(v.x); t[r][c4 + 1] = f2bf(v.y);
            t[r][c4 + 2] = f2bf(v.z); t[r][c4 + 3] = f2bf(v.w);
        }
    }
    __syncthreads();
    // store: 2 consecutive dst cols (one u32) x 8 dst rows per thread
    {
        int ce = (threadIdx.x & 31) * 2, r0 = (threadIdx.x >> 5) * 8;
#pragma unroll
        for (int j = 0; j < 8; j++) {
            int r = r0 + j;                            // dst row = source col
            u32 w = (u32)t[ce][r] | ((u32)t[ce + 1][r] << 16);
            *(u32*)&dst[(size_t)(x + r) * Dz + y + ce] = w;
        }
    }
}

// ---------------- GEMM: C = A[M,K](bf16) * Wt[N,K]^T(bf16), 128x128 tile ----
// global_load_lds staging + XOR-swizzled LDS (block cb of row r stored at
// cb ^ (r&7)) -> conflict-free ds_read_b128 fragment reads.
// MODE 0: fp32 row-major store. MODE 1: bf16 scatter (z=0/1 [B,H,S,HD] with
// FUSED RoPE applied to the fp32 accumulator via native v_sin/v_cos;
// z=2 [B,H,HD,S], no RoPE).
// XCD-aware block swizzle (T1): 512-block (x,y) plane, 512 % 8 == 0 ->
// bijective simple form; each XCD owns 64 contiguous work ids = 4 A-panels
// (2 MB, L2-resident). Verified r4: FETCH 198->147 MB, dur neutral
// (structure-bound at ~930 TF, the m97 ceiling).
template <int MODE>
__global__ void gemm_bt(const u16* __restrict__ A, const u16* __restrict__ BtBase,
                        void* __restrict__ CBase) {
    const int z = blockIdx.z;
    const u16* Bt = BtBase + (size_t)z * (Dz * Dz);
    const int tid = threadIdx.x, lane = tid & 63, wave = tid >> 6;
    const int ln = lane & 15, qd = lane >> 4;
    // XCD swizzle over the 512-block (x,y) plane (assumes gridDim = (16,32,z))
    const int lid = blockIdx.y * 16 + blockIdx.x;
    const int wid = (lid & 7) * 64 + (lid >> 3);
    const int m0 = (wid >> 4) * 128, n0 = (wid & 15) * 128;

    __shared__ __align__(16) u16 As[128][64];
    __shared__ __align__(16) u16 Bs[128][64];

    f32x4 acc[4][4];
#pragma unroll
    for (int i = 0; i < 4; i++)
#pragma unroll
        for (int j = 0; j < 4; j++) acc[i][j] = (f32x4){0.f, 0.f, 0.f, 0.f};

    const int wm = (wave >> 1) * 64, wn = (wave & 1) * 64;
    const int lr8 = lane >> 3;                         // row-within-8 (= row&7)
    const int bgo = (((lane & 7) ^ lr8) * 8);          // swizzled u16 col offset
    const int x7 = ln & 7;

    for (int k0 = 0; k0 < Dz; k0 += 64) {
        const u16* ga = A  + (size_t)(m0 + wave * 32 + lr8) * Dz + k0 + bgo;
        const u16* gb = Bt + (size_t)(n0 + wave * 32 + lr8) * Dz + k0 + bgo;
#pragma unroll
        for (int i = 0; i < 4; i++) {
            gl_lds16(ga + (size_t)(8 * i) * Dz, &As[wave * 32 + 8 * i][0]);
            gl_lds16(gb + (size_t)(8 * i) * Dz, &Bs[wave * 32 + 8 * i][0]);
        }
        __syncthreads();
#pragma unroll
        for (int kc = 0; kc < 2; kc++) {
            bf16x8 af[4], bff[4];
            const int cs = ((4 * kc + qd) ^ x7) * 8;   // swizzled fragment col
#pragma unroll
            for (int i = 0; i < 4; i++) {
                af[i]  = *(const bf16x8*)&As[wm + i * 16 + ln][cs];
                bff[i] = *(const bf16x8*)&Bs[wn + i * 16 + ln][cs];
            }
#pragma unroll
            for (int i = 0; i < 4; i++)
#pragma unroll
                for (int j = 0; j < 4; j++)
                    acc[i][j] = __builtin_amdgcn_mfma_f32_16x16x32_bf16(
                        af[i], bff[j], acc[i][j], 0, 0, 0);
        }
        __syncthreads();
    }

#pragma unroll
    for (int i = 0; i < 4; i++) {
#pragma unroll
        for (int j = 0; j < 4; j++) {
#pragma unroll
            for (int r = 0; r < 4; r++) {
                int row = m0 + wm + i * 16 + qd * 4 + r;
                int col = n0 + wn + j * 16 + ln;
                if (MODE == 0) {
                    ((float*)CBase)[(size_t)row * Dz + col] = acc[i][j][r];
                } else {
                    u16* C = (u16*)CBase + (size_t)z * ((size_t)Mz * Dz);
                    float v = acc[i][j][r];
                    int bb = row >> 11, ss = row & 2047;
                    int hh = col >> 7, hd = col & 127;
                    if (z == 2) {
                        C[((size_t)(bb * Hz + hh) * HDz + hd) * Sz + ss] = f2bf(v);
                    } else {
                        // fused RoPE: partner x[hd^1] lives in adjacent lane
                        // (col = ... + ln). rotate_half: even hd -> -x[hd+1],
                        // odd hd -> +x[hd-1]. theta = ss*10000^(-(hd&63)/64);
                        // computed in REVOLUTIONS for native v_sin/v_cos:
                        // fr = 10000^(-d/64)/(2pi) = exp2(-LG*d - log2(2pi)).
                        float partner = __shfl_xor(v, 1);
                        const float LG = 0.20762050593046017f;   // log2(10000)/64
                        const float L2PI = 2.6514961294723187f;  // log2(2*pi)
                        float fr = fexp2(-LG * (float)(hd & 63) - L2PI);
                        float sn, cn;
                        sincos_rev((float)ss * fr, &sn, &cn);
                        float rot = (hd & 1) ? partner : -partner;
                        float y = v * cn + rot * sn;
                        // 1/sqrt(HD)*log2(e) folded into Q (exp2-domain flash)
                        if (z == 0) y *= 0.12751771218027603f;
                        C[((size_t)(bb * Hz + hh) * Sz + ss) * HDz + hd] = f2bf(y);
                    }
                }
            }
        }
    }
}

// ---------------- causal flash attention, S^T formulation ------------------
// Q,K: [B,H,S,HD] (Q pre-scaled, RoPE fused upstream); Vt: [B,H,HD,S];
// O: [B,S,H*HD]. Block: 4 waves x 16 q-cols = 64 q; k-tiles of 64 keys.
// S^T = K*Q^T; O^T = V^T*P^T; l via ones-row of V. XOR-swizzled Ks/Vs.
// Load-balanced qt map: co-resident blocks {bid, bid+256, +512, +768} share a
// CU (bid mod 256 -> CU under round-robin dispatch) and get qt =
// {m, 31-m, 8+m, 23-m} (bijective over 0..31): per-CU key-sum is the constant
// 66 tiles, vs 80-4m for the old qt=31-(bid>>5) (21% tail imbalance).
// bh = bid&31 unchanged -> per-XCD K/V L2 locality preserved.
__global__ __launch_bounds__(256, 4)
void flash_attn(const u16* __restrict__ Q, const u16* __restrict__ Kk,
                const u16* __restrict__ Vt, u16* __restrict__ O) {
    const int tid = threadIdx.x, lane = tid & 63, wave = tid >> 6;
    const int ln = lane & 15, qd = lane >> 4;
    const int bh = blockIdx.x & 31;
    const int g = blockIdx.x >> 5;                     // 0..31
    const int gm = g & 7, gj = g >> 3;
    const int qt = (gj == 0) ? gm : (gj == 1) ? 31 - gm
                 : (gj == 2) ? 8 + gm : 23 - gm;
    const int b = bh >> 4, h = bh & 15;
    const int q0 = qt * 64;
    const u16* Qh = Q  + (size_t)bh * Sz * HDz;
    const u16* Kh = Kk + (size_t)bh * Sz * HDz;
    const u16* Vh = Vt + (size_t)bh * HDz * Sz;

    __shared__ __align__(16) u16 Ks[64][128];          // [key][d], swizzled blocks
    __shared__ __align__(16) u16 Vs[144][64];          // [d][key], swizzled; rows 128..143 ones-block

    // init ones-row block of Vs (row-uniform -> swizzle-invariant)
    for (int idx = tid; idx < 16 * 64; idx += 256) {
        int rr = idx >> 6, cc = idx & 63;
        Vs[128 + rr][cc] = (rr == 0) ? (u16)0x3F80 : (u16)0;
    }

    // Q B-fragments, direct from global (q = ln column, k = qd*8 + j)
    const int qabs = q0 + wave * 16 + ln;
    bf16x8 qf[4];
#pragma unroll
    for (int kc = 0; kc < 4; kc++) {
        uint4 t = *(const uint4*)(Qh + (size_t)qabs * HDz + kc * 32 + qd * 8);
        qf[kc] = *(const bf16x8*)&t;
    }

    float m_run = -INFINITY;
    f32x4 oa[9];                                       // O^T[d][q=ln]; oa[8] = l row
#pragma unroll
    for (int n = 0; n < 9; n++) oa[n] = (f32x4){0.f, 0.f, 0.f, 0.f};

    const int x7 = ln & 7;
    const int l4 = lane >> 4, c16 = lane & 15;         // K staging map
    const int lr8 = lane >> 3;                         // V staging map
    const int bgv = ((lane & 7) ^ lr8) * 8;

    for (int k0 = 0; k0 <= q0; k0 += 64) {
        // async stage K (64x128) and V (128x64), swizzled
        {
#pragma unroll
            for (int i = 0; i < 4; i++) {
                int rw = 4 * (i & 1) + l4;             // (row & 7)
                const u16* gk = Kh + (size_t)(k0 + 16 * wave + 4 * i + l4) * HDz
                                   + ((c16 ^ rw) * 8);
                gl_lds16(gk, &Ks[16 * wave + 4 * i][0]);
            }
            const u16* gv = Vh + (size_t)(32 * wave + lr8) * Sz + k0 + bgv;
#pragma unroll
            for (int i = 0; i < 4; i++)
                gl_lds16(gv + (size_t)(8 * i) * Sz, &Vs[32 * wave + 8 * i][0]);
        }
        __syncthreads();

        // S^T tile: C[key=mt*16+qd*4+r][q=ln]
        f32x4 sc4[4];
#pragma unroll
        for (int mt = 0; mt < 4; mt++) sc4[mt] = (f32x4){0.f, 0.f, 0.f, 0.f};
#pragma unroll
        for (int kc = 0; kc < 4; kc++) {
            const int cs = ((4 * kc + qd) ^ x7) * 8;
#pragma unroll
            for (int mt = 0; mt < 4; mt++) {
                bf16x8 kf = *(const bf16x8*)&Ks[mt * 16 + ln][cs];
                sc4[mt] = __builtin_amdgcn_mfma_f32_16x16x32_bf16(kf, qf[kc], sc4[mt], 0, 0, 0);
            }
        }
        if (k0 == q0) {                                // causal mask, diagonal tile only
#pragma unroll
            for (int mt = 0; mt < 4; mt++)
#pragma unroll
                for (int r = 0; r < 4; r++)
                    if (mt * 16 + qd * 4 + r > 16 * wave + ln) sc4[mt][r] = -3e38f;
        }

        // row max: in-register + cross-quad
        float rm = -3e38f;
#pragma unroll
        for (int mt = 0; mt < 4; mt++) {
            rm = fmaxf(rm, fmaxf(fmaxf(sc4[mt][0], sc4[mt][1]),
                                 fmaxf(sc4[mt][2], sc4[mt][3])));
        }
        rm = fmaxf(rm, __shfl_xor(rm, 16));
        rm = fmaxf(rm, __shfl_xor(rm, 32));
        float mn = fmaxf(m_run, rm);
        bool resc = (__ballot(mn > m_run) != 0ULL);
        float al = fexp2(m_run - mn);
        m_run = mn;
        if (resc) {
#pragma unroll
            for (int n = 0; n < 9; n++)
#pragma unroll
                for (int r = 0; r < 4; r++) oa[n][r] *= al;
        }

        // P = exp2(S - m), packed bf16 pairs: pku[mt*2+t] = keys(mt*16+qd*4+2t, +1)
        u32 pku[8];
#pragma unroll
        for (int mt = 0; mt < 4; mt++) {
#pragma unroll
            for (int t = 0; t < 2; t++)
                pku[mt * 2 + t] = pack_bf16_trunc(fexp2(sc4[mt][2 * t] - mn),
                                                  fexp2(sc4[mt][2 * t + 1] - mn));
        }

        // O^T += V^T * P^T  (B-frag of P^T built by register shuffle)
#pragma unroll
        for (int kc = 0; kc < 2; kc++) {
            union { u32 w[4]; bf16x8 v; } pb;
#pragma unroll
            for (int s = 0; s < 4; s++) {
                int srcl = ((2 * (qd & 1) + (s >> 1)) << 4) | ln;
                u32 a0 = (u32)__shfl((int)pku[4 * kc + (s & 1)], srcl);
                u32 a1 = (u32)__shfl((int)pku[4 * kc + 2 + (s & 1)], srcl);
                pb.w[s] = (qd & 2) ? a1 : a0;
            }
            const int cs = ((4 * kc + qd) ^ x7) * 8;
#pragma unroll
            for (int mt = 0; mt < 9; mt++) {
                bf16x8 vf = *(const bf16x8*)&Vs[mt * 16 + ln][cs];
                oa[mt] = __builtin_amdgcn_mfma_f32_16x16x32_bf16(vf, pb.v, oa[mt], 0, 0, 0);
            }
        }
        __syncthreads();
    }

    // l lives in quad 0, reg 0 of oa[8]; broadcast, normalize, store O[q][d]
    float l = __shfl(oa[8][0], ln);
    float linv = 1.0f / l;
    u16* op = O + ((size_t)b * Sz + qabs) * Dz + h * HDz;
#pragma unroll
    for (int mt = 0; mt < 8; mt++) {
        u32 w0 = pack_bf16_rn(oa[mt][0] * linv, oa[mt][1] * linv);
        u32 w1 = pack_bf16_rn(oa[mt][2] * linv, oa[mt][3] * linv);
        uint2 ww; ww.x = w0; ww.y = w1;
        *(uint2*)(op + mt * 16 + qd * 4) = ww;
    }
}

// ---------------------------------------------------------------------------
extern "C" void kernel_launch(void* const* d_in, const int* in_sizes, int n_in,
                              void* d_out, int out_size, void* d_ws, size_t ws_size,
                              hipStream_t stream) {
    const float* x  = (const float*)d_in[0];
    const float* Wq = (const float*)d_in[1];
    const float* Wk = (const float*)d_in[2];
    const float* Wv = (const float*)d_in[3];
    const float* Wo = (const float*)d_in[4];
    u16* ws  = (u16*)d_ws;

    u16* wt = ws;                       // 4 * 4,194,304 transposed bf16 weights (32 MB)
    u16* q  = ws + 16777216;            // [B,H,S,HD] (RoPE+scale fused in gemm)
    u16* kk = q + 8388608;              // [B,H,S,HD] (RoPE fused in gemm)
    u16* v  = kk + 8388608;             // [B,H,HD,S]
    u16* xb = v + 8388608;              // bf16(x); reused as o after gemm<1>
    u16* o  = xb;

    cvt_f32_bf16<<<dim3(4096), 256, 0, stream>>>(x, xb);
    transpose_w<<<dim3(32, 32, 4), 256, 0, stream>>>(Wq, Wk, Wv, Wo, wt);
    gemm_bt<1><<<dim3(16, 32, 3), 256, 0, stream>>>(xb, wt, q);
    flash_attn<<<dim3(1024), 256, 0, stream>>>(q, kk, v, o);
    gemm_bt<0><<<dim3(16, 32, 1), 256, 0, stream>>>(o, wt + 3 * 4194304, (float*)d_out);
}